// Round 8
// baseline (560.306 us; speedup 1.0000x reference)
//
#include <hip/hip_runtime.h>

// Problem constants
#define B_   8
#define SQ_  1024
#define SK_  1024
#define D_   512
#define H_   8
#define DFF_ 2048
#define L_   2
#define HD_  64
#define M_   8192   // B*SQ = B*SK rows

typedef __bf16 bf16;
using bf16x8 = __attribute__((ext_vector_type(8))) __bf16;
using f32x4  = __attribute__((ext_vector_type(4))) float;

__device__ inline f32x4 mfma16(bf16x8 a, bf16x8 b, f32x4 c) {
  return __builtin_amdgcn_mfma_f32_16x16x32_bf16(a, b, c, 0, 0, 0);
}

// async global->LDS DMA, 16B/lane; lane i lands at ldsbase + i*16 (m104/m108).
__device__ __forceinline__ void gl2lds16(const bf16* g, bf16* l) {
  __builtin_amdgcn_global_load_lds(
      (const __attribute__((address_space(1))) void*)g,
      (__attribute__((address_space(3))) void*)l, 16, 0, 0);
}

// ---------------------------------------------------------------------------
// Fused transpose+downcast for the four D x D weight stacks (WQ,WK,WV,WO).
// grid: (16, 16, 8)  z = weight*2 + layer. out[l][c][r] = (bf16)in[l][r][c]
// ---------------------------------------------------------------------------
struct TP4 { const float* in[4]; bf16* out[4]; };
__global__ __launch_bounds__(256) void transpose4_k(TP4 p) {
  __shared__ bf16 tile[32][33];
  int z = blockIdx.z, wsel = z >> 1, l = z & 1;
  const float* inp  = p.in[wsel]  + (size_t)l * D_ * D_;
  bf16*        outp = p.out[wsel] + (size_t)l * D_ * D_;
  int c0 = blockIdx.x * 32, r0 = blockIdx.y * 32;
  int tx = threadIdx.x & 31, ty = threadIdx.x >> 5;
#pragma unroll
  for (int i = 0; i < 32; i += 8)
    tile[ty + i][tx] = (bf16)inp[(size_t)(r0 + ty + i) * D_ + c0 + tx];
  __syncthreads();
#pragma unroll
  for (int i = 0; i < 32; i += 8)
    outp[(size_t)(c0 + ty + i) * D_ + r0 + tx] = tile[tx][ty + i];
}

// generic transpose+downcast (for Wf1/Wf2), grid (C/32, R/32, L)
__global__ __launch_bounds__(256) void transpose_k(
    const float* __restrict__ in, bf16* __restrict__ out, int R, int C) {
  __shared__ bf16 tile[32][33];
  const float* inp  = in  + (size_t)blockIdx.z * R * C;
  bf16*        outp = out + (size_t)blockIdx.z * R * C;
  int c0 = blockIdx.x * 32, r0 = blockIdx.y * 32;
  int tx = threadIdx.x & 31, ty = threadIdx.x >> 5;
#pragma unroll
  for (int i = 0; i < 32; i += 8)
    tile[ty + i][tx] = (bf16)inp[(size_t)(r0 + ty + i) * C + c0 + tx];
  __syncthreads();
#pragma unroll
  for (int i = 0; i < 32; i += 8)
    outp[(size_t)(c0 + ty + i) * R + r0 + tx] = tile[tx][ty + i];
}

// fused fp32->bf16 for q,k,v. grid: (M*D/1024, 3)
__global__ __launch_bounds__(256) void f2b3_k(
    const float* __restrict__ a, const float* __restrict__ b,
    const float* __restrict__ c, bf16* __restrict__ oa,
    bf16* __restrict__ ob, bf16* __restrict__ oc) {
  int which = blockIdx.y;
  const float* in = (which == 0) ? a : (which == 1) ? b : c;
  bf16* out = (which == 0) ? oa : (which == 1) ? ob : oc;
  int i = (blockIdx.x * 256 + threadIdx.x) * 4;
  float4 v = *(const float4*)&in[i];
  out[i] = (bf16)v.x; out[i + 1] = (bf16)v.y;
  out[i + 2] = (bf16)v.z; out[i + 3] = (bf16)v.w;
}

// ---------------------------------------------------------------------------
// GEMM: C[M,N] = A[M,K] bf16 * Bt[N,K]^T bf16 + bias(f32).
// XCD supergrouping: linear block id -> (c=id&7, j=id>>3), bx=c*8+(j&7),
// by=j>>3. Round-robin XCD assignment then gives XCD c the contiguous A-slice
// rows [c*1024, c*1024+1024) for ALL n-blocks -> A re-reads hit that XCD's L2
// (slice = 1-4 MB <= 4 MB L2). Requires gridDim.x == 64 (M/128).
// dbuf async DMA staging, one barrier per K-iter.
// ---------------------------------------------------------------------------
template<int BN>
__global__ __launch_bounds__(256) void gemm_t(
    const bf16* __restrict__ A, const bf16* __restrict__ Bt,
    const float* __restrict__ bias, bf16* __restrict__ Cb,
    float* __restrict__ Cf, int Nsz, int Ksz, int gelu) {
  constexpr int NI = BN / 32;
  __shared__ bf16 As[2][128 * 32];
  __shared__ bf16 Bs[2][BN * 32];
  const int tid = threadIdx.x;
  const int lin = blockIdx.x + blockIdx.y * gridDim.x;
  const int xcd = lin & 7, j = lin >> 3;
  const int m0 = (xcd * 8 + (j & 7)) * 128, n0 = (j >> 3) * BN;
  const int w = tid >> 6, lane = tid & 63, quad = lane >> 4, l16 = lane & 15;
  const int wm = (w & 1) << 6, wn = (w >> 1) * (BN / 2);
  const int r4 = lane >> 2;
  const int k8 = (lane & 3) * 8;
  f32x4 acc[4][NI] = {};

  auto stage = [&](int k0, int buf) {
    gl2lds16(&A[(size_t)(m0 + w * 16 + r4) * Ksz + k0 + k8],
             &As[buf][(w * 16) * 32]);
    gl2lds16(&A[(size_t)(m0 + (w + 4) * 16 + r4) * Ksz + k0 + k8],
             &As[buf][((w + 4) * 16) * 32]);
    gl2lds16(&Bt[(size_t)(n0 + w * 16 + r4) * Ksz + k0 + k8],
             &Bs[buf][(w * 16) * 32]);
    if constexpr (BN == 128)
      gl2lds16(&Bt[(size_t)(n0 + (w + 4) * 16 + r4) * Ksz + k0 + k8],
               &Bs[buf][((w + 4) * 16) * 32]);
  };

  stage(0, 0);
  __syncthreads();
  int buf = 0;
  for (int k0 = 0; k0 < Ksz; k0 += 32, buf ^= 1) {
    if (k0 + 32 < Ksz) stage(k0 + 32, buf ^ 1);
    bf16x8 af[4], bfr[NI];
#pragma unroll
    for (int i = 0; i < 4; i++)
      af[i] = *(const bf16x8*)&As[buf][(wm + i * 16 + l16) * 32 + quad * 8];
#pragma unroll
    for (int i = 0; i < NI; i++)
      bfr[i] = *(const bf16x8*)&Bs[buf][(wn + i * 16 + l16) * 32 + quad * 8];
#pragma unroll
    for (int mi = 0; mi < 4; mi++)
#pragma unroll
      for (int ni = 0; ni < NI; ni++)
        acc[mi][ni] = mfma16(af[mi], bfr[ni], acc[mi][ni]);
    __syncthreads();
  }
#pragma unroll
  for (int mi = 0; mi < 4; mi++)
#pragma unroll
    for (int ni = 0; ni < NI; ni++) {
      int col = n0 + wn + ni * 16 + l16;
      float bv = bias[col];
#pragma unroll
      for (int r = 0; r < 4; r++) {
        int row = m0 + wm + mi * 16 + quad * 4 + r;
        float x = acc[mi][ni][r] + bv;
        if (gelu) x = 0.5f * x * (1.0f + erff(x * 0.70710678118f));
        size_t idx = (size_t)row * Nsz + col;
        if (Cb) Cb[idx] = (bf16)x;
        if (Cf) Cf[idx] = x;
      }
    }
}

// ---------------------------------------------------------------------------
// fused V^T builder for both layers. grid: (SK/64, B*H, 2)
// ---------------------------------------------------------------------------
__global__ __launch_bounds__(256) void vtrans2_k(const bf16* __restrict__ vhh,
                                                 bf16* __restrict__ vt0,
                                                 bf16* __restrict__ vt1) {
  __shared__ bf16 sm[64][72];
  int kt = blockIdx.x, bh = blockIdx.y, z = blockIdx.z;
  int coloff = z ? D_ : 0;
  bf16* vt = z ? vt1 : vt0;
  int b = bh >> 3, h = bh & 7;
  int tid = threadIdx.x;
  for (int c = tid; c < 512; c += 256) {
    int key = c >> 3, off = (c & 7) * 8;
    *(uint4*)&sm[key][off] = *(const uint4*)
        &vhh[(size_t)(b * SK_ + kt * 64 + key) * (2 * D_) + coloff + h * 64 + off];
  }
  __syncthreads();
  for (int c = tid; c < 512; c += 256) {
    int hd = c >> 3, koff = (c & 7) * 8;
    bf16 tmp[8];
#pragma unroll
    for (int j = 0; j < 8; j++) tmp[j] = sm[koff + j][hd];
    *(uint4*)&vt[(size_t)(bh * 64 + hd) * SK_ + kt * 64 + koff] = *(uint4*)tmp;
  }
}

// ---------------------------------------------------------------------------
// Flash attention, Realformer prev recompute, no max-subtraction.
// 128 Q-rows/block (4 waves x 2 mi). dbuf DMA staging, one barrier/tile.
// Ps is PER-MI (16 rows/wave) with stride 72 -> rows stagger 16 banks,
// 2-way conflicts only (r7's stride-64 Ps caused 4-way collisions = 25% of
// CU cycles in SQ_LDS_BANK_CONFLICT). V-frags hoisted once per tile.
// LDS: HAS0 57.6KB (2 blk/CU), else 41.6KB (3 blk/CU).
// grid: (SQ/128, B*H), block 256.
// ---------------------------------------------------------------------------
template<bool HAS0>
__global__ __launch_bounds__(256) void attn_t(
    const bf16* __restrict__ qh, const bf16* __restrict__ qh0,
    const bf16* __restrict__ kh, const bf16* __restrict__ kh0, int kstride,
    const bf16* __restrict__ vt, const float* __restrict__ scale,
    const float* __restrict__ extra, int li, bf16* __restrict__ ctx) {
  __shared__ bf16 Ks[2 * 2 * 2048];                 // [buf][half][64*32]
  __shared__ bf16 K0s[HAS0 ? 2 * 2 * 2048 : 64];
  __shared__ bf16 Vs[2 * 2 * 2048];                 // [buf][half][hd*32]
  __shared__ bf16 Ps[4][16 * 72];                   // per-wave, per-mi reuse
  int qt = blockIdx.x, bh = blockIdx.y;
  int b = bh >> 3, h = bh & 7;
  int tid = threadIdx.x, w = tid >> 6, lane = tid & 63;
  int quad = lane >> 4, l16 = lane & 15;
  const int r4 = lane >> 2, c4 = (lane & 3) * 8;
  float eff1 = scale[li] * fminf(fmaxf(extra[li], 0.01f), 50.0f);
  float eff0 = HAS0 ? scale[li - 1] * fminf(fmaxf(extra[li - 1], 0.01f), 50.0f) : 0.f;
  // Q frags: wave w rows qt*128 + w*32 + mi*16 + l16 (A: m=l16, k=quad*8+j)
  bf16x8 aq[2][2], aq0[2][2];
#pragma unroll
  for (int mi = 0; mi < 2; mi++) {
    int qrow = b * SQ_ + qt * 128 + w * 32 + mi * 16 + l16;
    const bf16* qp = qh + (size_t)qrow * D_ + h * 64 + quad * 8;
    aq[mi][0] = *(const bf16x8*)qp; aq[mi][1] = *(const bf16x8*)(qp + 32);
#pragma unroll
    for (int k2 = 0; k2 < 2; k2++)
#pragma unroll
      for (int j = 0; j < 8; j++)
        aq[mi][k2][j] = (bf16)((float)aq[mi][k2][j] * eff1);
    if constexpr (HAS0) {
      const bf16* qp0 = qh0 + (size_t)qrow * D_ + h * 64 + quad * 8;
      aq0[mi][0] = *(const bf16x8*)qp0; aq0[mi][1] = *(const bf16x8*)(qp0 + 32);
#pragma unroll
      for (int k2 = 0; k2 < 2; k2++)
#pragma unroll
        for (int j = 0; j < 8; j++)
          aq0[mi][k2][j] = (bf16)((float)aq0[mi][k2][j] * eff0);
    }
  }
  bf16x8 ones;
#pragma unroll
  for (int j = 0; j < 8; j++) ones[j] = (bf16)1.0f;

  f32x4 o[2][4] = {};
  f32x4 ol[2] = {};

  auto stage = [&](int kt, int bufi) {
    size_t kg = (size_t)(b * SK_ + kt * 64 + w * 16 + r4) * kstride + h * 64 + c4;
    gl2lds16(&kh[kg],      &Ks[(bufi * 2 + 0) * 2048 + (w * 16) * 32]);
    gl2lds16(&kh[kg + 32], &Ks[(bufi * 2 + 1) * 2048 + (w * 16) * 32]);
    if constexpr (HAS0) {
      gl2lds16(&kh0[kg],      &K0s[(bufi * 2 + 0) * 2048 + (w * 16) * 32]);
      gl2lds16(&kh0[kg + 32], &K0s[(bufi * 2 + 1) * 2048 + (w * 16) * 32]);
    }
    size_t vg = (size_t)(bh * 64 + w * 16 + r4) * SK_ + kt * 64 + c4;
    gl2lds16(&vt[vg],      &Vs[(bufi * 2 + 0) * 2048 + (w * 16) * 32]);
    gl2lds16(&vt[vg + 32], &Vs[(bufi * 2 + 1) * 2048 + (w * 16) * 32]);
  };

  stage(0, 0);
  __syncthreads();
  int buf = 0;
  for (int kt = 0; kt < SK_ / 64; kt++, buf ^= 1) {
    if (kt + 1 < SK_ / 64) stage(kt + 1, buf ^ 1);
    // hoist V frags once per tile (reused across mi)
    bf16x8 bv[2][4];
#pragma unroll
    for (int kk = 0; kk < 2; kk++)
#pragma unroll
      for (int ni = 0; ni < 4; ni++)
        bv[kk][ni] = *(const bf16x8*)&Vs[kk * 2048 + buf * 4096 +
                                         (ni * 16 + l16) * 32 + quad * 8];
#pragma unroll
    for (int mi = 0; mi < 2; mi++) {
      // S = (eff1*Q1)K1^T [+ (eff0*Q0)K0^T]; exp -> Ps (per-wave, per-mi)
#pragma unroll
      for (int ni = 0; ni < 4; ni++) {
        int ro = (ni * 16 + l16) * 32 + quad * 8;
        f32x4 t = {};
        t = mfma16(aq[mi][0], *(const bf16x8*)&Ks[0 * 2048 + buf * 4096 + ro], t);
        t = mfma16(aq[mi][1], *(const bf16x8*)&Ks[1 * 2048 + buf * 4096 + ro], t);
        if constexpr (HAS0) {
          t = mfma16(aq0[mi][0], *(const bf16x8*)&K0s[0 * 2048 + buf * 4096 + ro], t);
          t = mfma16(aq0[mi][1], *(const bf16x8*)&K0s[1 * 2048 + buf * 4096 + ro], t);
        }
#pragma unroll
        for (int r = 0; r < 4; r++)
          Ps[w][(quad * 4 + r) * 72 + ni * 16 + l16] = (bf16)__expf(t[r]);
      }
      // PV + row-sum (same-wave LDS ordering; no barrier)
#pragma unroll
      for (int kk = 0; kk < 2; kk++) {
        bf16x8 ap = *(const bf16x8*)&Ps[w][l16 * 72 + kk * 32 + quad * 8];
        ol[mi] = mfma16(ap, ones, ol[mi]);
#pragma unroll
        for (int ni = 0; ni < 4; ni++)
          o[mi][ni] = mfma16(ap, bv[kk][ni], o[mi][ni]);
      }
    }
    __syncthreads();
  }
  // epilogue: O /= l
#pragma unroll
  for (int mi = 0; mi < 2; mi++)
#pragma unroll
    for (int ni = 0; ni < 4; ni++)
#pragma unroll
      for (int r = 0; r < 4; r++) {
        int row = b * SQ_ + qt * 128 + w * 32 + mi * 16 + quad * 4 + r;
        ctx[(size_t)row * D_ + h * 64 + ni * 16 + l16] =
            (bf16)(o[mi][ni][r] / ol[mi][r]);
      }
}

// ---------------------------------------------------------------------------
// Gated residual + post-LN  (unchanged)
// ---------------------------------------------------------------------------
__global__ __launch_bounds__(256) void ln_k(
    const float* __restrict__ cur_in, const float* __restrict__ add,
    const float* __restrict__ gate, const float* __restrict__ g,
    const float* __restrict__ bb, float* __restrict__ outf,
    bf16* __restrict__ outb) {
  int row = blockIdx.x, tid = threadIdx.x;
  float gv = gate[0];
  float sp = gv > 20.f ? gv : log1pf(expf(gv));
  size_t base = (size_t)row * D_;
  int c0 = tid * 2;
  float2 c2 = *(const float2*)&cur_in[base + c0];
  float2 a2 = *(const float2*)&add[base + c0];
  float x0 = c2.x + sp * a2.x, x1 = c2.y + sp * a2.y;
  float s = x0 + x1, s2 = x0 * x0 + x1 * x1;
#pragma unroll
  for (int m = 1; m < 64; m <<= 1) {
    s += __shfl_xor(s, m);
    s2 += __shfl_xor(s2, m);
  }
  __shared__ float sa[4], sb[4];
  int w = tid >> 6;
  if ((tid & 63) == 0) { sa[w] = s; sb[w] = s2; }
  __syncthreads();
  s = sa[0] + sa[1] + sa[2] + sa[3];
  s2 = sb[0] + sb[1] + sb[2] + sb[3];
  float mu = s * (1.f / D_);
  float var = s2 * (1.f / D_) - mu * mu;
  float rs = rsqrtf(var + 1e-5f);
  float y0 = (x0 - mu) * rs * g[c0] + bb[c0];
  float y1 = (x1 - mu) * rs * g[c0 + 1] + bb[c0 + 1];
  if (outf) { float2 y; y.x = y0; y.y = y1; *(float2*)&outf[base + c0] = y; }
  if (outb) { outb[base + c0] = (bf16)y0; outb[base + c0 + 1] = (bf16)y1; }
}

// ---------------------------------------------------------------------------
extern "C" void kernel_launch(void* const* d_in, const int* in_sizes, int n_in,
                              void* d_out, int out_size, void* d_ws,
                              size_t ws_size, hipStream_t stream) {
  const float* qin = (const float*)d_in[0];
  const float* kin = (const float*)d_in[1];
  const float* vin = (const float*)d_in[2];
  const float* WQ  = (const float*)d_in[3];
  const float* bQ  = (const float*)d_in[4];
  const float* WK  = (const float*)d_in[5];
  const float* bK  = (const float*)d_in[6];
  const float* WV  = (const float*)d_in[7];
  const float* bV  = (const float*)d_in[8];
  const float* WO  = (const float*)d_in[9];
  const float* bO  = (const float*)d_in[10];
  const float* Wf1 = (const float*)d_in[11];
  const float* bf1 = (const float*)d_in[12];
  const float* Wf2 = (const float*)d_in[13];
  const float* bf2 = (const float*)d_in[14];
  const float* l1g = (const float*)d_in[15];
  const float* l1b = (const float*)d_in[16];
  const float* l2g = (const float*)d_in[17];
  const float* l2b = (const float*)d_in[18];
  const float* sc  = (const float*)d_in[19];
  const float* ex  = (const float*)d_in[20];
  const float* ga  = (const float*)d_in[21];
  const float* gf  = (const float*)d_in[22];

  char* p = (char*)d_ws;
  auto alloc = [&](size_t bytes) {
    void* r = (void*)p;
    p += (bytes + 255) & ~(size_t)255;
    return r;
  };
  bf16* WQt  = (bf16*)alloc((size_t)L_ * D_ * D_ * 2);
  bf16* WKt  = (bf16*)alloc((size_t)L_ * D_ * D_ * 2);
  bf16* WVt  = (bf16*)alloc((size_t)L_ * D_ * D_ * 2);
  bf16* WOt  = (bf16*)alloc((size_t)L_ * D_ * D_ * 2);
  bf16* Wf1t = (bf16*)alloc((size_t)L_ * D_ * DFF_ * 2);
  bf16* Wf2t = (bf16*)alloc((size_t)L_ * D_ * DFF_ * 2);
  float* cur  = (float*)alloc((size_t)M_ * D_ * 4);
  bf16* curb  = (bf16*)alloc((size_t)M_ * D_ * 2);
  bf16* qb    = (bf16*)alloc((size_t)M_ * D_ * 2);
  bf16* kb    = (bf16*)alloc((size_t)M_ * D_ * 2);
  bf16* vb    = (bf16*)alloc((size_t)M_ * D_ * 2);
  bf16* khh   = (bf16*)alloc((size_t)M_ * 2 * D_ * 2);  // both layers
  bf16* vhh   = (bf16*)alloc((size_t)M_ * 2 * D_ * 2);
  bf16* qh0b  = (bf16*)alloc((size_t)M_ * D_ * 2);
  bf16* qh1b  = (bf16*)alloc((size_t)M_ * D_ * 2);
  bf16* vt0   = (bf16*)alloc((size_t)M_ * D_ * 2);
  bf16* vt1   = (bf16*)alloc((size_t)M_ * D_ * 2);
  bf16* ctx   = (bf16*)alloc((size_t)M_ * D_ * 2);
  float* proj = (float*)alloc((size_t)M_ * D_ * 4);
  bf16* ffmid = (bf16*)alloc((size_t)M_ * DFF_ * 2);
  float* ffout = (float*)alloc((size_t)M_ * D_ * 4);

  // prep (fused)
  TP4 tp; tp.in[0] = WQ; tp.in[1] = WK; tp.in[2] = WV; tp.in[3] = WO;
  tp.out[0] = WQt; tp.out[1] = WKt; tp.out[2] = WVt; tp.out[3] = WOt;
  transpose4_k<<<dim3(16, 16, 8), 256, 0, stream>>>(tp);
  transpose_k<<<dim3(DFF_ / 32, D_ / 32, L_), 256, 0, stream>>>(Wf1, Wf1t, D_, DFF_);
  transpose_k<<<dim3(D_ / 32, DFF_ / 32, L_), 256, 0, stream>>>(Wf2, Wf2t, DFF_, D_);
  f2b3_k<<<dim3((M_ * D_) / 1024, 3), 256, 0, stream>>>(qin, kin, vin, qb, kb, vb);

  // hoisted: K/V projections for BOTH layers in one N=1024 GEMM each
  gemm_t<128><<<dim3(M_ / 128, 8), 256, 0, stream>>>(
      kb, WKt, bK, khh, nullptr, 2 * D_, D_, 0);
  gemm_t<128><<<dim3(M_ / 128, 8), 256, 0, stream>>>(
      vb, WVt, bV, vhh, nullptr, 2 * D_, D_, 0);
  vtrans2_k<<<dim3(SK_ / 64, B_ * H_, 2), 256, 0, stream>>>(vhh, vt0, vt1);
  // layer-0 Q projection
  gemm_t<64><<<dim3(M_ / 128, 8), 256, 0, stream>>>(
      qb, WQt, bQ, qh0b, nullptr, D_, D_, 0);

  for (int li = 0; li < L_; li++) {
    if (li > 0)
      gemm_t<64><<<dim3(M_ / 128, 8), 256, 0, stream>>>(
          curb, WQt + (size_t)li * D_ * D_, bQ + li * D_, qh1b, nullptr, D_, D_, 0);
    if (li == 0)
      attn_t<false><<<dim3(SQ_ / 128, B_ * H_), 256, 0, stream>>>(
          qh0b, qh0b, khh, khh, 2 * D_, vt0, sc, ex, 0, ctx);
    else
      attn_t<true><<<dim3(SQ_ / 128, B_ * H_), 256, 0, stream>>>(
          qh1b, qh0b, khh + (size_t)li * D_, khh, 2 * D_, vt1, sc, ex, 1, ctx);
    gemm_t<64><<<dim3(M_ / 128, 8), 256, 0, stream>>>(
        ctx, WOt + (size_t)li * D_ * D_, bO + li * D_, nullptr, proj, D_, D_, 0);
    ln_k<<<M_, 256, 0, stream>>>((li == 0) ? qin : cur, proj, ga + li,
                                 l1g + li * D_, l1b + li * D_, cur, curb);
    gemm_t<128><<<dim3(M_ / 128, DFF_ / 128), 256, 0, stream>>>(
        curb, Wf1t + (size_t)li * D_ * DFF_, bf1 + li * DFF_, ffmid, nullptr,
        DFF_, D_, 1);
    gemm_t<64><<<dim3(M_ / 128, 8), 256, 0, stream>>>(
        ffmid, Wf2t + (size_t)li * DFF_ * D_, bf2 + li * D_, nullptr, ffout,
        D_, DFF_, 0);
    ln_k<<<M_, 256, 0, stream>>>(cur, ffout, gf + li, l2g + li * D_,
                                 l2b + li * D_,
                                 (li == L_ - 1) ? (float*)d_out : cur,
                                 (li == L_ - 1) ? nullptr : curb);
  }
}

// Round 9
// 548.976 us; speedup vs baseline: 1.0206x; 1.0206x over previous
//
#include <hip/hip_runtime.h>

// Problem constants
#define B_   8
#define SQ_  1024
#define SK_  1024
#define D_   512
#define H_   8
#define DFF_ 2048
#define L_   2
#define HD_  64
#define M_   8192   // B*SQ = B*SK rows

typedef __bf16 bf16;
using bf16x8 = __attribute__((ext_vector_type(8))) __bf16;
using f32x4  = __attribute__((ext_vector_type(4))) float;

__device__ inline f32x4 mfma16(bf16x8 a, bf16x8 b, f32x4 c) {
  return __builtin_amdgcn_mfma_f32_16x16x32_bf16(a, b, c, 0, 0, 0);
}

// async global->LDS DMA, 16B/lane; lane i lands at ldsbase + i*16 (m104/m108).
__device__ __forceinline__ void gl2lds16(const bf16* g, bf16* l) {
  __builtin_amdgcn_global_load_lds(
      (const __attribute__((address_space(1))) void*)g,
      (__attribute__((address_space(3))) void*)l, 16, 0, 0);
}

// fast GELU (tanh form): max |err| vs exact-erf GELU ~1e-3 -> negligible after
// Wf2 (std 0.02) propagation vs 0.105 output tolerance. 1 v_exp vs ~30-op erff.
__device__ __forceinline__ float gelu_fast(float x) {
  float u = 1.5957691216f * (x + 0.044715f * x * x * x);  // 2*0.7978845608
  return x / (1.0f + __expf(-u));  // 0.5x(1+tanh(u/2)) == x*sigmoid(u)
}

// ---------------------------------------------------------------------------
// Fused transpose+downcast for the four D x D weight stacks (WQ,WK,WV,WO).
// grid: (16, 16, 8)  z = weight*2 + layer. out[l][c][r] = (bf16)in[l][r][c]
// ---------------------------------------------------------------------------
struct TP4 { const float* in[4]; bf16* out[4]; };
__global__ __launch_bounds__(256) void transpose4_k(TP4 p) {
  __shared__ bf16 tile[32][33];
  int z = blockIdx.z, wsel = z >> 1, l = z & 1;
  const float* inp  = p.in[wsel]  + (size_t)l * D_ * D_;
  bf16*        outp = p.out[wsel] + (size_t)l * D_ * D_;
  int c0 = blockIdx.x * 32, r0 = blockIdx.y * 32;
  int tx = threadIdx.x & 31, ty = threadIdx.x >> 5;
#pragma unroll
  for (int i = 0; i < 32; i += 8)
    tile[ty + i][tx] = (bf16)inp[(size_t)(r0 + ty + i) * D_ + c0 + tx];
  __syncthreads();
#pragma unroll
  for (int i = 0; i < 32; i += 8)
    outp[(size_t)(c0 + ty + i) * D_ + r0 + tx] = tile[tx][ty + i];
}

// generic transpose+downcast (for Wf1/Wf2), grid (C/32, R/32, L)
__global__ __launch_bounds__(256) void transpose_k(
    const float* __restrict__ in, bf16* __restrict__ out, int R, int C) {
  __shared__ bf16 tile[32][33];
  const float* inp  = in  + (size_t)blockIdx.z * R * C;
  bf16*        outp = out + (size_t)blockIdx.z * R * C;
  int c0 = blockIdx.x * 32, r0 = blockIdx.y * 32;
  int tx = threadIdx.x & 31, ty = threadIdx.x >> 5;
#pragma unroll
  for (int i = 0; i < 32; i += 8)
    tile[ty + i][tx] = (bf16)inp[(size_t)(r0 + ty + i) * C + c0 + tx];
  __syncthreads();
#pragma unroll
  for (int i = 0; i < 32; i += 8)
    outp[(size_t)(c0 + ty + i) * R + r0 + tx] = tile[tx][ty + i];
}

// fused fp32->bf16 for q,k,v. grid: (M*D/1024, 3)
__global__ __launch_bounds__(256) void f2b3_k(
    const float* __restrict__ a, const float* __restrict__ b,
    const float* __restrict__ c, bf16* __restrict__ oa,
    bf16* __restrict__ ob, bf16* __restrict__ oc) {
  int which = blockIdx.y;
  const float* in = (which == 0) ? a : (which == 1) ? b : c;
  bf16* out = (which == 0) ? oa : (which == 1) ? ob : oc;
  int i = (blockIdx.x * 256 + threadIdx.x) * 4;
  float4 v = *(const float4*)&in[i];
  out[i] = (bf16)v.x; out[i + 1] = (bf16)v.y;
  out[i + 2] = (bf16)v.z; out[i + 3] = (bf16)v.w;
}

// ---------------------------------------------------------------------------
// GEMM: C[M,N] = A[M,K] bf16 * Bt[N,K]^T bf16 + bias(f32).
// Natural block mapping (r8's XCD supergroup remap REGRESSED FFN1 58->73 us:
// natural x-fastest order already gives each XCD 8 m-blocks x all n; the remap
// only reordered it and hurt temporal/write locality).
// dbuf async DMA staging, one barrier per K-iter.
// ---------------------------------------------------------------------------
template<int BN>
__global__ __launch_bounds__(256) void gemm_t(
    const bf16* __restrict__ A, const bf16* __restrict__ Bt,
    const float* __restrict__ bias, bf16* __restrict__ Cb,
    float* __restrict__ Cf, int Nsz, int Ksz, int gelu) {
  constexpr int NI = BN / 32;
  __shared__ bf16 As[2][128 * 32];
  __shared__ bf16 Bs[2][BN * 32];
  const int tid = threadIdx.x;
  const int m0 = blockIdx.x * 128, n0 = blockIdx.y * BN;
  const int w = tid >> 6, lane = tid & 63, quad = lane >> 4, l16 = lane & 15;
  const int wm = (w & 1) << 6, wn = (w >> 1) * (BN / 2);
  const int r4 = lane >> 2;
  const int k8 = (lane & 3) * 8;
  f32x4 acc[4][NI] = {};

  auto stage = [&](int k0, int buf) {
    gl2lds16(&A[(size_t)(m0 + w * 16 + r4) * Ksz + k0 + k8],
             &As[buf][(w * 16) * 32]);
    gl2lds16(&A[(size_t)(m0 + (w + 4) * 16 + r4) * Ksz + k0 + k8],
             &As[buf][((w + 4) * 16) * 32]);
    gl2lds16(&Bt[(size_t)(n0 + w * 16 + r4) * Ksz + k0 + k8],
             &Bs[buf][(w * 16) * 32]);
    if constexpr (BN == 128)
      gl2lds16(&Bt[(size_t)(n0 + (w + 4) * 16 + r4) * Ksz + k0 + k8],
               &Bs[buf][((w + 4) * 16) * 32]);
  };

  stage(0, 0);
  __syncthreads();
  int buf = 0;
  for (int k0 = 0; k0 < Ksz; k0 += 32, buf ^= 1) {
    if (k0 + 32 < Ksz) stage(k0 + 32, buf ^ 1);
    bf16x8 af[4], bfr[NI];
#pragma unroll
    for (int i = 0; i < 4; i++)
      af[i] = *(const bf16x8*)&As[buf][(wm + i * 16 + l16) * 32 + quad * 8];
#pragma unroll
    for (int i = 0; i < NI; i++)
      bfr[i] = *(const bf16x8*)&Bs[buf][(wn + i * 16 + l16) * 32 + quad * 8];
#pragma unroll
    for (int mi = 0; mi < 4; mi++)
#pragma unroll
      for (int ni = 0; ni < NI; ni++)
        acc[mi][ni] = mfma16(af[mi], bfr[ni], acc[mi][ni]);
    __syncthreads();
  }
#pragma unroll
  for (int mi = 0; mi < 4; mi++)
#pragma unroll
    for (int ni = 0; ni < NI; ni++) {
      int col = n0 + wn + ni * 16 + l16;
      float bv = bias[col];
#pragma unroll
      for (int r = 0; r < 4; r++) {
        int row = m0 + wm + mi * 16 + quad * 4 + r;
        float x = acc[mi][ni][r] + bv;
        if (gelu) x = gelu_fast(x);
        size_t idx = (size_t)row * Nsz + col;
        if (Cb) Cb[idx] = (bf16)x;
        if (Cf) Cf[idx] = x;
      }
    }
}

// ---------------------------------------------------------------------------
// fused V^T builder for both layers. grid: (SK/64, B*H, 2)
// ---------------------------------------------------------------------------
__global__ __launch_bounds__(256) void vtrans2_k(const bf16* __restrict__ vhh,
                                                 bf16* __restrict__ vt0,
                                                 bf16* __restrict__ vt1) {
  __shared__ bf16 sm[64][72];
  int kt = blockIdx.x, bh = blockIdx.y, z = blockIdx.z;
  int coloff = z ? D_ : 0;
  bf16* vt = z ? vt1 : vt0;
  int b = bh >> 3, h = bh & 7;
  int tid = threadIdx.x;
  for (int c = tid; c < 512; c += 256) {
    int key = c >> 3, off = (c & 7) * 8;
    *(uint4*)&sm[key][off] = *(const uint4*)
        &vhh[(size_t)(b * SK_ + kt * 64 + key) * (2 * D_) + coloff + h * 64 + off];
  }
  __syncthreads();
  for (int c = tid; c < 512; c += 256) {
    int hd = c >> 3, koff = (c & 7) * 8;
    bf16 tmp[8];
#pragma unroll
    for (int j = 0; j < 8; j++) tmp[j] = sm[koff + j][hd];
    *(uint4*)&vt[(size_t)(bh * 64 + hd) * SK_ + kt * 64 + koff] = *(uint4*)tmp;
  }
}

// ---------------------------------------------------------------------------
// Flash attention (unchanged from r8): Realformer prev recompute, no
// max-subtraction, 128 Q-rows/block, dbuf DMA, per-mi Ps stride-72.
// ---------------------------------------------------------------------------
template<bool HAS0>
__global__ __launch_bounds__(256) void attn_t(
    const bf16* __restrict__ qh, const bf16* __restrict__ qh0,
    const bf16* __restrict__ kh, const bf16* __restrict__ kh0, int kstride,
    const bf16* __restrict__ vt, const float* __restrict__ scale,
    const float* __restrict__ extra, int li, bf16* __restrict__ ctx) {
  __shared__ bf16 Ks[2 * 2 * 2048];                 // [buf][half][64*32]
  __shared__ bf16 K0s[HAS0 ? 2 * 2 * 2048 : 64];
  __shared__ bf16 Vs[2 * 2 * 2048];                 // [buf][half][hd*32]
  __shared__ bf16 Ps[4][16 * 72];                   // per-wave, per-mi reuse
  int qt = blockIdx.x, bh = blockIdx.y;
  int b = bh >> 3, h = bh & 7;
  int tid = threadIdx.x, w = tid >> 6, lane = tid & 63;
  int quad = lane >> 4, l16 = lane & 15;
  const int r4 = lane >> 2, c4 = (lane & 3) * 8;
  float eff1 = scale[li] * fminf(fmaxf(extra[li], 0.01f), 50.0f);
  float eff0 = HAS0 ? scale[li - 1] * fminf(fmaxf(extra[li - 1], 0.01f), 50.0f) : 0.f;
  bf16x8 aq[2][2], aq0[2][2];
#pragma unroll
  for (int mi = 0; mi < 2; mi++) {
    int qrow = b * SQ_ + qt * 128 + w * 32 + mi * 16 + l16;
    const bf16* qp = qh + (size_t)qrow * D_ + h * 64 + quad * 8;
    aq[mi][0] = *(const bf16x8*)qp; aq[mi][1] = *(const bf16x8*)(qp + 32);
#pragma unroll
    for (int k2 = 0; k2 < 2; k2++)
#pragma unroll
      for (int j = 0; j < 8; j++)
        aq[mi][k2][j] = (bf16)((float)aq[mi][k2][j] * eff1);
    if constexpr (HAS0) {
      const bf16* qp0 = qh0 + (size_t)qrow * D_ + h * 64 + quad * 8;
      aq0[mi][0] = *(const bf16x8*)qp0; aq0[mi][1] = *(const bf16x8*)(qp0 + 32);
#pragma unroll
      for (int k2 = 0; k2 < 2; k2++)
#pragma unroll
        for (int j = 0; j < 8; j++)
          aq0[mi][k2][j] = (bf16)((float)aq0[mi][k2][j] * eff0);
    }
  }
  bf16x8 ones;
#pragma unroll
  for (int j = 0; j < 8; j++) ones[j] = (bf16)1.0f;

  f32x4 o[2][4] = {};
  f32x4 ol[2] = {};

  auto stage = [&](int kt, int bufi) {
    size_t kg = (size_t)(b * SK_ + kt * 64 + w * 16 + r4) * kstride + h * 64 + c4;
    gl2lds16(&kh[kg],      &Ks[(bufi * 2 + 0) * 2048 + (w * 16) * 32]);
    gl2lds16(&kh[kg + 32], &Ks[(bufi * 2 + 1) * 2048 + (w * 16) * 32]);
    if constexpr (HAS0) {
      gl2lds16(&kh0[kg],      &K0s[(bufi * 2 + 0) * 2048 + (w * 16) * 32]);
      gl2lds16(&kh0[kg + 32], &K0s[(bufi * 2 + 1) * 2048 + (w * 16) * 32]);
    }
    size_t vg = (size_t)(bh * 64 + w * 16 + r4) * SK_ + kt * 64 + c4;
    gl2lds16(&vt[vg],      &Vs[(bufi * 2 + 0) * 2048 + (w * 16) * 32]);
    gl2lds16(&vt[vg + 32], &Vs[(bufi * 2 + 1) * 2048 + (w * 16) * 32]);
  };

  stage(0, 0);
  __syncthreads();
  int buf = 0;
  for (int kt = 0; kt < SK_ / 64; kt++, buf ^= 1) {
    if (kt + 1 < SK_ / 64) stage(kt + 1, buf ^ 1);
    bf16x8 bv[2][4];
#pragma unroll
    for (int kk = 0; kk < 2; kk++)
#pragma unroll
      for (int ni = 0; ni < 4; ni++)
        bv[kk][ni] = *(const bf16x8*)&Vs[kk * 2048 + buf * 4096 +
                                         (ni * 16 + l16) * 32 + quad * 8];
#pragma unroll
    for (int mi = 0; mi < 2; mi++) {
#pragma unroll
      for (int ni = 0; ni < 4; ni++) {
        int ro = (ni * 16 + l16) * 32 + quad * 8;
        f32x4 t = {};
        t = mfma16(aq[mi][0], *(const bf16x8*)&Ks[0 * 2048 + buf * 4096 + ro], t);
        t = mfma16(aq[mi][1], *(const bf16x8*)&Ks[1 * 2048 + buf * 4096 + ro], t);
        if constexpr (HAS0) {
          t = mfma16(aq0[mi][0], *(const bf16x8*)&K0s[0 * 2048 + buf * 4096 + ro], t);
          t = mfma16(aq0[mi][1], *(const bf16x8*)&K0s[1 * 2048 + buf * 4096 + ro], t);
        }
#pragma unroll
        for (int r = 0; r < 4; r++)
          Ps[w][(quad * 4 + r) * 72 + ni * 16 + l16] = (bf16)__expf(t[r]);
      }
#pragma unroll
      for (int kk = 0; kk < 2; kk++) {
        bf16x8 ap = *(const bf16x8*)&Ps[w][l16 * 72 + kk * 32 + quad * 8];
        ol[mi] = mfma16(ap, ones, ol[mi]);
#pragma unroll
        for (int ni = 0; ni < 4; ni++)
          o[mi][ni] = mfma16(ap, bv[kk][ni], o[mi][ni]);
      }
    }
    __syncthreads();
  }
#pragma unroll
  for (int mi = 0; mi < 2; mi++)
#pragma unroll
    for (int ni = 0; ni < 4; ni++)
#pragma unroll
      for (int r = 0; r < 4; r++) {
        int row = b * SQ_ + qt * 128 + w * 32 + mi * 16 + quad * 4 + r;
        ctx[(size_t)row * D_ + h * 64 + ni * 16 + l16] =
            (bf16)(o[mi][ni][r] / ol[mi][r]);
      }
}

// ---------------------------------------------------------------------------
// Gated residual + post-LN  (unchanged)
// ---------------------------------------------------------------------------
__global__ __launch_bounds__(256) void ln_k(
    const float* __restrict__ cur_in, const float* __restrict__ add,
    const float* __restrict__ gate, const float* __restrict__ g,
    const float* __restrict__ bb, float* __restrict__ outf,
    bf16* __restrict__ outb) {
  int row = blockIdx.x, tid = threadIdx.x;
  float gv = gate[0];
  float sp = gv > 20.f ? gv : log1pf(expf(gv));
  size_t base = (size_t)row * D_;
  int c0 = tid * 2;
  float2 c2 = *(const float2*)&cur_in[base + c0];
  float2 a2 = *(const float2*)&add[base + c0];
  float x0 = c2.x + sp * a2.x, x1 = c2.y + sp * a2.y;
  float s = x0 + x1, s2 = x0 * x0 + x1 * x1;
#pragma unroll
  for (int m = 1; m < 64; m <<= 1) {
    s += __shfl_xor(s, m);
    s2 += __shfl_xor(s2, m);
  }
  __shared__ float sa[4], sb[4];
  int w = tid >> 6;
  if ((tid & 63) == 0) { sa[w] = s; sb[w] = s2; }
  __syncthreads();
  s = sa[0] + sa[1] + sa[2] + sa[3];
  s2 = sb[0] + sb[1] + sb[2] + sb[3];
  float mu = s * (1.f / D_);
  float var = s2 * (1.f / D_) - mu * mu;
  float rs = rsqrtf(var + 1e-5f);
  float y0 = (x0 - mu) * rs * g[c0] + bb[c0];
  float y1 = (x1 - mu) * rs * g[c0 + 1] + bb[c0 + 1];
  if (outf) { float2 y; y.x = y0; y.y = y1; *(float2*)&outf[base + c0] = y; }
  if (outb) { outb[base + c0] = (bf16)y0; outb[base + c0 + 1] = (bf16)y1; }
}

// ---------------------------------------------------------------------------
extern "C" void kernel_launch(void* const* d_in, const int* in_sizes, int n_in,
                              void* d_out, int out_size, void* d_ws,
                              size_t ws_size, hipStream_t stream) {
  const float* qin = (const float*)d_in[0];
  const float* kin = (const float*)d_in[1];
  const float* vin = (const float*)d_in[2];
  const float* WQ  = (const float*)d_in[3];
  const float* bQ  = (const float*)d_in[4];
  const float* WK  = (const float*)d_in[5];
  const float* bK  = (const float*)d_in[6];
  const float* WV  = (const float*)d_in[7];
  const float* bV  = (const float*)d_in[8];
  const float* WO  = (const float*)d_in[9];
  const float* bO  = (const float*)d_in[10];
  const float* Wf1 = (const float*)d_in[11];
  const float* bf1 = (const float*)d_in[12];
  const float* Wf2 = (const float*)d_in[13];
  const float* bf2 = (const float*)d_in[14];
  const float* l1g = (const float*)d_in[15];
  const float* l1b = (const float*)d_in[16];
  const float* l2g = (const float*)d_in[17];
  const float* l2b = (const float*)d_in[18];
  const float* sc  = (const float*)d_in[19];
  const float* ex  = (const float*)d_in[20];
  const float* ga  = (const float*)d_in[21];
  const float* gf  = (const float*)d_in[22];

  char* p = (char*)d_ws;
  auto alloc = [&](size_t bytes) {
    void* r = (void*)p;
    p += (bytes + 255) & ~(size_t)255;
    return r;
  };
  bf16* WQt  = (bf16*)alloc((size_t)L_ * D_ * D_ * 2);
  bf16* WKt  = (bf16*)alloc((size_t)L_ * D_ * D_ * 2);
  bf16* WVt  = (bf16*)alloc((size_t)L_ * D_ * D_ * 2);
  bf16* WOt  = (bf16*)alloc((size_t)L_ * D_ * D_ * 2);
  bf16* Wf1t = (bf16*)alloc((size_t)L_ * D_ * DFF_ * 2);
  bf16* Wf2t = (bf16*)alloc((size_t)L_ * D_ * DFF_ * 2);
  float* cur  = (float*)alloc((size_t)M_ * D_ * 4);
  bf16* curb  = (bf16*)alloc((size_t)M_ * D_ * 2);
  bf16* qb    = (bf16*)alloc((size_t)M_ * D_ * 2);
  bf16* kb    = (bf16*)alloc((size_t)M_ * D_ * 2);
  bf16* vb    = (bf16*)alloc((size_t)M_ * D_ * 2);
  bf16* khh   = (bf16*)alloc((size_t)M_ * 2 * D_ * 2);  // both layers
  bf16* vhh   = (bf16*)alloc((size_t)M_ * 2 * D_ * 2);
  bf16* qh0b  = (bf16*)alloc((size_t)M_ * D_ * 2);
  bf16* qh1b  = (bf16*)alloc((size_t)M_ * D_ * 2);
  bf16* vt0   = (bf16*)alloc((size_t)M_ * D_ * 2);
  bf16* vt1   = (bf16*)alloc((size_t)M_ * D_ * 2);
  bf16* ctx   = (bf16*)alloc((size_t)M_ * D_ * 2);
  float* proj = (float*)alloc((size_t)M_ * D_ * 4);
  bf16* ffmid = (bf16*)alloc((size_t)M_ * DFF_ * 2);
  float* ffout = (float*)alloc((size_t)M_ * D_ * 4);

  // prep (fused)
  TP4 tp; tp.in[0] = WQ; tp.in[1] = WK; tp.in[2] = WV; tp.in[3] = WO;
  tp.out[0] = WQt; tp.out[1] = WKt; tp.out[2] = WVt; tp.out[3] = WOt;
  transpose4_k<<<dim3(16, 16, 8), 256, 0, stream>>>(tp);
  transpose_k<<<dim3(DFF_ / 32, D_ / 32, L_), 256, 0, stream>>>(Wf1, Wf1t, D_, DFF_);
  transpose_k<<<dim3(D_ / 32, DFF_ / 32, L_), 256, 0, stream>>>(Wf2, Wf2t, DFF_, D_);
  f2b3_k<<<dim3((M_ * D_) / 1024, 3), 256, 0, stream>>>(qin, kin, vin, qb, kb, vb);

  // hoisted: K/V projections for BOTH layers in one N=1024 GEMM each
  gemm_t<128><<<dim3(M_ / 128, 8), 256, 0, stream>>>(
      kb, WKt, bK, khh, nullptr, 2 * D_, D_, 0);
  gemm_t<128><<<dim3(M_ / 128, 8), 256, 0, stream>>>(
      vb, WVt, bV, vhh, nullptr, 2 * D_, D_, 0);
  vtrans2_k<<<dim3(SK_ / 64, B_ * H_, 2), 256, 0, stream>>>(vhh, vt0, vt1);
  // layer-0 Q projection
  gemm_t<64><<<dim3(M_ / 128, 8), 256, 0, stream>>>(
      qb, WQt, bQ, qh0b, nullptr, D_, D_, 0);

  for (int li = 0; li < L_; li++) {
    if (li > 0)
      gemm_t<64><<<dim3(M_ / 128, 8), 256, 0, stream>>>(
          curb, WQt + (size_t)li * D_ * D_, bQ + li * D_, qh1b, nullptr, D_, D_, 0);
    if (li == 0)
      attn_t<false><<<dim3(SQ_ / 128, B_ * H_), 256, 0, stream>>>(
          qh0b, qh0b, khh, khh, 2 * D_, vt0, sc, ex, 0, ctx);
    else
      attn_t<true><<<dim3(SQ_ / 128, B_ * H_), 256, 0, stream>>>(
          qh1b, qh0b, khh + (size_t)li * D_, khh, 2 * D_, vt1, sc, ex, 1, ctx);
    gemm_t<64><<<dim3(M_ / 128, 8), 256, 0, stream>>>(
        ctx, WOt + (size_t)li * D_ * D_, bO + li * D_, nullptr, proj, D_, D_, 0);
    ln_k<<<M_, 256, 0, stream>>>((li == 0) ? qin : cur, proj, ga + li,
                                 l1g + li * D_, l1b + li * D_, cur, curb);
    gemm_t<128><<<dim3(M_ / 128, DFF_ / 128), 256, 0, stream>>>(
        curb, Wf1t + (size_t)li * D_ * DFF_, bf1 + li * DFF_, ffmid, nullptr,
        DFF_, D_, 1);
    gemm_t<64><<<dim3(M_ / 128, 8), 256, 0, stream>>>(
        ffmid, Wf2t + (size_t)li * DFF_ * D_, bf2 + li * D_, nullptr, ffout,
        D_, DFF_, 0);
    ln_k<<<M_, 256, 0, stream>>>(cur, ffout, gf + li, l2g + li * D_,
                                 l2b + li * D_,
                                 (li == L_ - 1) ? (float*)d_out : cur,
                                 (li == L_ - 1) ? nullptr : curb);
  }
}